// Round 15
// baseline (427.697 us; speedup 1.0000x reference)
//
#include <hip/hip_runtime.h>
#include <math.h>

typedef unsigned short u16;
typedef unsigned int   u32;
typedef __attribute__((ext_vector_type(8))) short bf16x8;
typedef __attribute__((ext_vector_type(4))) short bf16x4;
typedef __attribute__((ext_vector_type(4))) float f32x4;

#if __has_builtin(__builtin_amdgcn_mfma_f32_16x16x16_bf16)
#define MFMA16(a,b,c) __builtin_amdgcn_mfma_f32_16x16x16_bf16(a,b,c,0,0,0)
#else
#define MFMA16(a,b,c) __builtin_amdgcn_mfma_f32_16x16x16bf16_1k(a,b,c,0,0,0)
#endif

// ---- static device workspace (no dependence on ws_size) ----
__device__ __align__(256) u16 g_ws[23068672];
__device__ __align__(16)  u16 g_cvt[2576904];
__device__ u32  g_mm[8];        // sortable-uint min[3] / max[3]
__device__ int  g_modes[32];    // 1 = input was fp32, 0 = bf16

#define G_OFF   0
#define KH_OFF  0
#define VT_OFF  2097152
#define KV_OFF  8388608
#define QB_OFF  10485760
#define QH_OFF  16777216

// g_cvt offsets (u16 units), inputs 0..26
#define ENC_C   0
#define COORD_C 2097152
#define MTOK_C  2195456
#define PEW1_C  2195712
#define PEB1_C  2196480
#define PEG_C   2196736
#define PEBE_C  2196992
#define PEW2_C  2197248
#define PEB2_C  2262784
#define WQ_C    2263040
#define BQ_C    2328576
#define WK_C    2328832
#define BK_C    2394368
#define WV_C    2394624
#define BV_C    2460160
#define WO_C    2460416
#define BO_C    2525952
#define ANG_C   2526208
#define ANB_C   2526464
#define DW1_C   2526720
#define DB1_C   2559488
#define DG_C    2559616
#define DBE_C   2559744
#define DW2_C   2559872
#define DB2_C   2576256
#define DW3_C   2576384
#define DB3_C   2576896

__device__ const int g_cn[27] = {
    2097152,98304,256,768,256,256,256,65536,256,
    65536,256,65536,256,65536,256,65536,256,256,256,
    32768,128,128,128,16384,128,512,4};
__device__ const int g_coff[27] = {
    ENC_C,COORD_C,MTOK_C,PEW1_C,PEB1_C,PEG_C,PEBE_C,PEW2_C,PEB2_C,
    WQ_C,BQ_C,WK_C,BK_C,WV_C,BV_C,WO_C,BO_C,ANG_C,ANB_C,
    DW1_C,DB1_C,DG_C,DBE_C,DW2_C,DB2_C,DW3_C,DB3_C};

struct P27 { const void* p[27]; };

__device__ __forceinline__ float bf2f(u16 v){ return __uint_as_float(((u32)v)<<16); }
__device__ __forceinline__ u16 f2bf(float f){
    u32 u = __float_as_uint(f);
    return (u16)((u + 0x7FFFu + ((u>>16)&1u)) >> 16);
}
__device__ __forceinline__ float gelu_f(float x){
    return 0.5f*x*(1.0f + erff(x*0.70710678118654752440f));
}
__device__ __forceinline__ u32 f2key(float f){
    u32 u = __float_as_uint(f);
    return (u & 0x80000000u) ? ~u : (u | 0x80000000u);
}
__device__ __forceinline__ float key2f(u32 k){
    u32 u = (k & 0x80000000u) ? (k & 0x7FFFFFFFu) : ~k;
    return __uint_as_float(u);
}
__device__ __forceinline__ float exp2_fast(float x){ return __builtin_amdgcn_exp2f(x); }

// --------------------------------------------------- dtype detect ----
__global__ __launch_bounds__(256) void k_detect(P27 P){
    int i = blockIdx.x, tid = threadIdx.x;
    if(i == 0 && tid < 3){ g_mm[tid] = 0xFFFFFFFFu; g_mm[3+tid] = 0u; }
    int n = g_cn[i];
    const u16* s16 = (const u16*)P.p[i];
    __shared__ int c_nz, c_ib, c_nzE;
    if(tid==0){ c_nz=0; c_ib=0; c_nzE=0; }
    __syncthreads();
    int S = n < 2048 ? n : 2048;
    int nz=0, ib=0, nzE=0;
    for(int w = tid; w < S; w += 256){
        u16 v = s16[w];
        if((v & 0x7FFF) != 0){
            nz++;
            int e = (v>>7)&0xFF;
            if(e >= 0x70 && e <= 0x8F) ib++;
            if((w & 1) == 0) nzE++;
        }
    }
    atomicAdd(&c_nz, nz); atomicAdd(&c_ib, ib); atomicAdd(&c_nzE, nzE);
    __syncthreads();
    if(tid==0){
        int totE = (S+1)>>1, totO = S>>1;
        int nzO = c_nz - c_nzE;
        bool A = (c_ib*10 < c_nz*8);
        bool B = (nzO*10 >= totO*9) && (c_nzE*10 <= totE);
        g_modes[i] = (c_nz > 0 && (A || B)) ? 1 : 0;
    }
}

// ------------------------- vectorized convert (+ fused coord min/max) ----
__global__ __launch_bounds__(256) void k_cvt(P27 P){
    int i = blockIdx.x;
    int n4 = g_cn[i] >> 2;
    int mode = g_modes[i];
    u16* dst = g_cvt + g_coff[i];
    int v0 = blockIdx.y*256 + threadIdx.x, step = gridDim.y*256;
    bool isCoord = (i == 1);
    u32 kmn[3] = {0xFFFFFFFFu,0xFFFFFFFFu,0xFFFFFFFFu};
    u32 kmx[3] = {0u,0u,0u};
    if(mode){
        const float4* src = (const float4*)P.p[i];
        for(int v = v0; v < n4; v += step){
            float4 f = src[v];
            ushort4 o = make_ushort4(f2bf(f.x), f2bf(f.y), f2bf(f.z), f2bf(f.w));
            *(ushort4*)&dst[v*4] = o;
            if(isCoord){
                u16 oo[4] = {o.x,o.y,o.z,o.w};
                for(int j=0;j<4;j++){
                    int c = (v + j) % 3;     // (4v+j)%3 == (v+j)%3
                    u32 k = f2key(bf2f(oo[j]));
                    kmn[c] = min(kmn[c], k); kmx[c] = max(kmx[c], k);
                }
            }
        }
    } else {
        const ushort4* src = (const ushort4*)P.p[i];
        for(int v = v0; v < n4; v += step){
            ushort4 o = src[v];
            *(ushort4*)&dst[v*4] = o;
            if(isCoord){
                u16 oo[4] = {o.x,o.y,o.z,o.w};
                for(int j=0;j<4;j++){
                    int c = (v + j) % 3;
                    u32 k = f2key(bf2f(oo[j]));
                    kmn[c] = min(kmn[c], k); kmx[c] = max(kmx[c], k);
                }
            }
        }
    }
    if(isCoord){
        for(int m=1;m<64;m<<=1){
            for(int c=0;c<3;c++){
                kmn[c] = min(kmn[c], (u32)__shfl_xor((int)kmn[c], m));
                kmx[c] = max(kmx[c], (u32)__shfl_xor((int)kmx[c], m));
            }
        }
        if((threadIdx.x & 63) == 0){
            for(int c=0;c<3;c++){
                atomicMin(&g_mm[c], kmn[c]);
                atomicMax(&g_mm[3+c], kmx[c]);
            }
        }
    }
}

// ----------------------------------------------- pos-embed front (to G) ----
__global__ __launch_bounds__(256) void k_posfront(){
    const u16* coord = g_cvt + COORD_C;
    const u16* w1 = g_cvt + PEW1_C;
    const u16* b1 = g_cvt + PEB1_C;
    const u16* g  = g_cvt + PEG_C;
    const u16* be = g_cvt + PEBE_C;
    u16* G = g_ws + G_OFF;
    int tid = threadIdx.x, wid = tid>>6, lane = tid&63;
    int r = blockIdx.x*4 + wid;
    float cn[3];
    for(int c=0;c<3;c++){
        float mn = key2f(g_mm[c]);
        float span = fmaxf(key2f(g_mm[3+c]) - mn, 1.0f);
        cn[c] = (bf2f(coord[r*3+c]) - mn) * (1.0f/span);
    }
    int j0 = lane*4;
    float t[4];
    for(int jj=0;jj<4;jj++){
        int j = j0+jj;
        t[jj] = bf2f(w1[j*3+0])*cn[0] + bf2f(w1[j*3+1])*cn[1] + bf2f(w1[j*3+2])*cn[2] + bf2f(b1[j]);
    }
    float s  = t[0]+t[1]+t[2]+t[3];
    float s2 = t[0]*t[0]+t[1]*t[1]+t[2]*t[2]+t[3]*t[3];
    for(int m=1;m<64;m<<=1){ s += __shfl_xor(s,m); s2 += __shfl_xor(s2,m); }
    float mean = s*(1.0f/256.0f);
    float var  = s2*(1.0f/256.0f) - mean*mean;
    float rs   = rsqrtf(var + 1e-5f);
    u16 o[4];
    for(int jj=0;jj<4;jj++){
        int j = j0+jj;
        float y = (t[jj]-mean)*rs*bf2f(g[j]) + bf2f(be[j]);
        o[jj] = f2bf(gelu_f(y));
    }
    *(ushort4*)&G[(size_t)r*256 + j0] = make_ushort4(o[0],o[1],o[2],o[3]);
}

// ------------------------------------------------------------- GEMM-BT ----
// 64x128 tile with ASYNC global_load_lds staging (verified r11).
// LDS unpadded (stride 32), both-sides block swizzle for bank conflicts.
// EPI 1: pos scatter (KV = C+encoded / Qb = C+mask_token)
template<int EPI>
__global__ __launch_bounds__(256) void k_gemm(int aOff, int bwOff, int biasOff,
        int out0Off, int out1Off, int add0Off, int add1Off, int M, int N, int K){
    const u16* A  = g_ws + aOff;
    const u16* Bw = g_cvt + bwOff;
    const u16* bias = g_cvt + biasOff;
    u16* out0 = g_ws + out0Off;
    u16* out1 = g_ws + out1Off;
    const u16* add0 = g_cvt + add0Off;
    const u16* add1 = g_cvt + add1Off;
    __shared__ __align__(16) u16 sA[64*32];
    __shared__ __align__(16) u16 sB[128*32];
    int tid = threadIdx.x, wid = tid>>6, lane = tid&63;
    int quad = lane>>4, l16 = lane&15;
    int bM = blockIdx.x*64, bN = blockIdx.y*128;
    int waveM = (wid&1)*32, waveN = (wid>>1)*64;
    int rq = quad ^ ((l16>>1)&3);          // swizzled read block
    int sqA = ((tid&3) ^ ((tid>>3)&3))*8;  // swizzled source col (A, e=tid)
    f32x4 acc[2][4];
    for(int i=0;i<2;i++) for(int j=0;j<4;j++) acc[i][j] = (f32x4){0.f,0.f,0.f,0.f};

    for(int k0=0;k0<K;k0+=32){
        {
            int row = tid>>2;
            __builtin_amdgcn_global_load_lds(
                (const u32*)&A[(size_t)(bM+row)*K + k0 + sqA],
                (u32*)&sA[(size_t)(tid>>6)*512], 16, 0, 0);
        }
        for(int i=0;i<2;i++){
            int e = tid + 256*i;
            int row = e>>2, sq = ((e&3) ^ ((e>>3)&3))*8;
            __builtin_amdgcn_global_load_lds(
                (const u32*)&Bw[(size_t)(bN+row)*K + k0 + sq],
                (u32*)&sB[(size_t)(e>>6)*512], 16, 0, 0);
        }
        __syncthreads();
        bf16x8 af[2], bfr[4];
        for(int rt=0;rt<2;rt++) af [rt] = *(const bf16x8*)&sA[(waveM+rt*16+l16)*32 + rq*8];
        for(int ct=0;ct<4;ct++) bfr[ct] = *(const bf16x8*)&sB[(waveN+ct*16+l16)*32 + rq*8];
        for(int rt=0;rt<2;rt++)
            for(int ct=0;ct<4;ct++)
                acc[rt][ct] = __builtin_amdgcn_mfma_f32_16x16x32_bf16(af[rt], bfr[ct], acc[rt][ct], 0,0,0);
        __syncthreads();
    }

    for(int ct=0;ct<4;ct++){
        int col = bN + waveN + ct*16 + l16;
        float bv = bf2f(bias[col]);
        for(int rt=0;rt<2;rt++){
            int rbase = bM + waveM + rt*16 + quad*4;
            for(int r=0;r<4;r++){
                int row = rbase + r;
                float v = acc[rt][ct][r] + bv;
                if(EPI==0){
                    out0[(size_t)row*N + col] = f2bf(v);
                } else {
                    int b = row>>11, p = row&2047;
                    if(p < 512){
                        int kr = (b<<9) + p;
                        out0[(size_t)kr*256 + col] = f2bf(v + bf2f(add0[(size_t)kr*256 + col]));
                    } else {
                        int qr = b*1536 + (p-512);
                        out1[(size_t)qr*256 + col] = f2bf(v + bf2f(add1[col]));
                    }
                }
            }
        }
    }
}

// -------------------------------------- fused Q/K/V projection GEMM ----
// 64-row tiles, async global_load_lds staging (verified r11).
// bx [0,128) K ; [128,256) V ; [256,640) Q
// V scattered into VT with the key-swizzle; Q written PRE-SCALED by cl.
__global__ __launch_bounds__(256) void k_qkv(){
    int bx = blockIdx.x;
    const u16* A = g_ws + KV_OFF;
    const u16* Bw; const u16* bias; int rowBase, mode;
    if(bx < 128)     { rowBase = bx*64;             Bw = g_cvt+WK_C; bias = g_cvt+BK_C; mode = 0; }
    else if(bx < 256){ rowBase = (bx-128)*64;       Bw = g_cvt+WV_C; bias = g_cvt+BV_C; mode = 1; }
    else             { rowBase = 8192+(bx-256)*64;  Bw = g_cvt+WQ_C; bias = g_cvt+BQ_C; mode = 2; }
    __shared__ __align__(16) u16 sA[64*32];
    __shared__ __align__(16) u16 sB[128*32];
    int tid = threadIdx.x, wid = tid>>6, lane = tid&63;
    int quad = lane>>4, l16 = lane&15;
    int bN = blockIdx.y*128;
    int waveM = (wid&1)*32, waveN = (wid>>1)*64;
    int rq = quad ^ ((l16>>1)&3);
    int sqA = ((tid&3) ^ ((tid>>3)&3))*8;
    f32x4 acc[2][4];
    for(int i=0;i<2;i++) for(int j=0;j<4;j++) acc[i][j] = (f32x4){0.f,0.f,0.f,0.f};

    for(int k0=0;k0<256;k0+=32){
        {
            int row = tid>>2;
            __builtin_amdgcn_global_load_lds(
                (const u32*)&A[(size_t)(rowBase+row)*256 + k0 + sqA],
                (u32*)&sA[(size_t)(tid>>6)*512], 16, 0, 0);
        }
        for(int i=0;i<2;i++){
            int e = tid + 256*i;
            int row = e>>2, sq = ((e&3) ^ ((e>>3)&3))*8;
            __builtin_amdgcn_global_load_lds(
                (const u32*)&Bw[(size_t)(bN+row)*256 + k0 + sq],
                (u32*)&sB[(size_t)(e>>6)*512], 16, 0, 0);
        }
        __syncthreads();
        bf16x8 af[2], bfr[4];
        for(int rt=0;rt<2;rt++) af [rt] = *(const bf16x8*)&sA[(waveM+rt*16+l16)*32 + rq*8];
        for(int ct=0;ct<4;ct++) bfr[ct] = *(const bf16x8*)&sB[(waveN+ct*16+l16)*32 + rq*8];
        for(int rt=0;rt<2;rt++)
            for(int ct=0;ct<4;ct++)
                acc[rt][ct] = __builtin_amdgcn_mfma_f32_16x16x32_bf16(af[rt], bfr[ct], acc[rt][ct], 0,0,0);
        __syncthreads();
    }

    u16* Kh = g_ws + KH_OFF;
    u16* VT = g_ws + VT_OFF;
    u16* Qh = g_ws + QH_OFF;
    const float cl = 0.17677669529663688f * 1.4426950408889634f;  // scale*log2e
    for(int ct=0;ct<4;ct++){
        int col = bN + waveN + ct*16 + l16;
        float bv = bf2f(bias[col]);
        for(int rt=0;rt<2;rt++){
            int rbase = rowBase + waveM + rt*16 + quad*4;
            for(int r=0;r<4;r++){
                int row = rbase + r;
                float v = acc[rt][ct][r] + bv;
                if(mode==0){
                    Kh[(size_t)row*256 + col] = f2bf(v);
                } else if(mode==1){
                    int h = col>>5, d = col&31;
                    int b = row>>9, key = row&511;
                    int t = key>>4, q4 = (key>>2)&3, j = key&3;
                    int keyp = ((t>>1)<<5) + (q4<<3) + ((t&1)<<2) + j;
                    VT[(((size_t)(b*8+h)*32 + d)<<9) + keyp] = f2bf(v);
                } else {
                    Qh[(size_t)(row-8192)*256 + col] = f2bf(v * cl);
                }
            }
        }
    }
}

// ----------------------------------------------------------- attention ----
// Swapped-operand QK^T, fully in-register P, Q pre-scaled (verified r7/r11).
// This round's single delta: per-wave q-tile DOUBLED 32->64 rows (qt 2->4),
// grid-y 12->6. K-staging + barriers per q-row halve (inverse of r9's
// verified dose-response). Arrays indexed only by the unrolled qt.
__global__ __launch_bounds__(256, 6) void k_attn(int y0){
    u16* Qh = g_ws + QH_OFF;
    const u16* Kh = g_ws + KH_OFF;
    const u16* VT = g_ws + VT_OFF;
    __shared__ __align__(16) u16 sK[256*40];     // 20 KB
    int tid = threadIdx.x, wid = tid>>6, lane = tid&63;
    int quad = lane>>4, l16 = lane&15;
    int bh = blockIdx.x, b = bh>>3, h = bh&7;

    const u16* kb = &Kh[(size_t)(b*512)*256 + h*32];
    const u16* vb = &VT[(size_t)bh*32*512];
    int qbase = b*1536 + (y0 + blockIdx.y)*256 + wid*64;

    bf16x8 qf[4];
    #pragma unroll
    for(int qt=0;qt<4;qt++)
        qf[qt] = *(const bf16x8*)&Qh[(size_t)(qbase + qt*16 + l16)*256 + h*32 + quad*8];
    f32x4 O[4][2];
    float rs_[4] = {0.f, 0.f, 0.f, 0.f};
    #pragma unroll
    for(int qt=0;qt<4;qt++){
        O[qt][0] = (f32x4){0.f,0.f,0.f,0.f}; O[qt][1] = (f32x4){0.f,0.f,0.f,0.f};
    }

    for(int ph=0; ph<2; ph++){
        for(int i=0;i<4;i++){
            int e = tid + 256*i;
            int row = e>>2, kc = (e&3)*8;
            *(uint4*)&sK[row*40+kc] = *(const uint4*)&kb[(size_t)(ph*256+row)*256 + kc];
        }
        __syncthreads();
        for(int c=0;c<2;c++){
            #pragma unroll
            for(int tp=0;tp<4;tp++){
                // V fragments for this k-pair: d=l16 (v0) and d=16+l16 (v1)
                const u16* vp = vb + (size_t)l16*512 + ph*256 + c*128 + tp*32 + quad*8;
                bf16x8 v0 = *(const bf16x8*)vp;
                bf16x8 v1 = *(const bf16x8*)(vp + 16*512);
                bf16x4 v0lo = __builtin_shufflevector(v0, v0, 0,1,2,3);
                bf16x4 v0hi = __builtin_shufflevector(v0, v0, 4,5,6,7);
                bf16x4 v1lo = __builtin_shufflevector(v1, v1, 0,1,2,3);
                bf16x4 v1hi = __builtin_shufflevector(v1, v1, 4,5,6,7);
                bf16x8 kf0 = *(const bf16x8*)&sK[(c*128 + tp*32      + l16)*40 + quad*8];
                bf16x8 kf1 = *(const bf16x8*)&sK[(c*128 + tp*32 + 16 + l16)*40 + quad*8];
                #pragma unroll
                for(int qt=0; qt<4; qt++){
                    f32x4 s0 = __builtin_amdgcn_mfma_f32_16x16x32_bf16(kf0, qf[qt], (f32x4){0.f,0.f,0.f,0.f}, 0,0,0);
                    f32x4 s1 = __builtin_amdgcn_mfma_f32_16x16x32_bf16(kf1, qf[qt], (f32x4){0.f,0.f,0.f,0.f}, 0,0,0);
                    float e0 = exp2_fast(s0[0]), e1 = exp2_fast(s0[1]);
                    float e2 = exp2_fast(s0[2]), e3 = exp2_fast(s0[3]);
                    float e4 = exp2_fast(s1[0]), e5 = exp2_fast(s1[1]);
                    float e6 = exp2_fast(s1[2]), e7 = exp2_fast(s1[3]);
                    rs_[qt] += (e0+e1+e2+e3) + (e4+e5+e6+e7);
                    bf16x4 p0, p1;
                    p0[0]=(short)f2bf(e0); p0[1]=(short)f2bf(e1);
                    p0[2]=(short)f2bf(e2); p0[3]=(short)f2bf(e3);
                    p1[0]=(short)f2bf(e4); p1[1]=(short)f2bf(e5);
                    p1[2]=(short)f2bf(e6); p1[3]=(short)f2bf(e7);
                    O[qt][0] = MFMA16(p0, v0lo, O[qt][0]);
                    O[qt][0] = MFMA16(p1, v0hi, O[qt][0]);
                    O[qt][1] = MFMA16(p0, v1lo, O[qt][1]);
                    O[qt][1] = MFMA16(p1, v1hi, O[qt][1]);
                }
            }
        }
        __syncthreads();
    }
    #pragma unroll
    for(int qt=0;qt<4;qt++){
        float rsum = rs_[qt];
        rsum += __shfl_xor(rsum, 16);
        rsum += __shfl_xor(rsum, 32);
        for(int r=0;r<4;r++){
            float inv = 1.0f / __shfl(rsum, quad*4 + r);
            size_t row = (size_t)(qbase + qt*16 + quad*4 + r);
            Qh[row*256 + h*32      + l16] = f2bf(O[qt][0][r]*inv);
            Qh[row*256 + h*32 + 16 + l16] = f2bf(O[qt][1][r]*inv);
        }
    }
}

// ---------------- fused wo-GEMM + residual add + LayerNorm (in-place Qb) ----
// 64x256 tile (full N per block) so each row's LN is block-local.
__global__ __launch_bounds__(256) void k_wo_ln(){
    const u16* A    = g_ws + QH_OFF;
    const u16* Bw   = g_cvt + WO_C;
    const u16* bias = g_cvt + BO_C;
    u16* Qb = g_ws + QB_OFF;
    const u16* g  = g_cvt + ANG_C;
    const u16* be = g_cvt + ANB_C;
    __shared__ __align__(16) u16 sA[64*40];
    __shared__ __align__(16) u16 sB[256*40];
    __shared__ float sS[2][64], sS2[2][64];
    int tid = threadIdx.x, wid = tid>>6, lane = tid&63;
    int quad = lane>>4, l16 = lane&15;
    int bM = blockIdx.x*64;
    int waveM = (wid&1)*32, waveN = (wid>>1)*128;
    f32x4 acc[2][8];
    for(int i=0;i<2;i++) for(int j=0;j<8;j++) acc[i][j] = (f32x4){0.f,0.f,0.f,0.f};

    for(int k0=0;k0<256;k0+=32){
        {
            int row = tid>>2, kc = (tid&3)*8;
            *(uint4*)&sA[row*40+kc] = *(const uint4*)&A[(size_t)(bM+row)*256 + k0 + kc];
        }
        for(int i=0;i<4;i++){
            int e = tid + 256*i;
            int row = e>>2, kc = (e&3)*8;
            *(uint4*)&sB[row*40+kc] = *(const uint4*)&Bw[(size_t)row*256 + k0 + kc];
        }
        __syncthreads();
        bf16x8 af[2], bfr[8];
        for(int rt=0;rt<2;rt++) af [rt] = *(const bf16x8*)&sA[(waveM+rt*16+l16)*40 + quad*8];
        for(int ct=0;ct<8;ct++) bfr[ct] = *(const bf16x8*)&sB[(waveN+ct*16+l16)*40 + quad*8];
        for(int rt=0;rt<2;rt++)
            for(int ct=0;ct<8;ct++)
                acc[rt][ct] = __builtin_amdgcn_mfma_f32_16x16x32_bf16(af[rt], bfr[ct], acc[rt][ct], 0,0,0);
        __syncthreads();
    }

    // x = q + attn_out + bias (kept fp32 in acc), accumulate LN partials
    float s[2][4], s2[2][4];
    for(int rt=0;rt<2;rt++){
        for(int r=0;r<4;r++){ s[rt][r]=0.f; s2[rt][r]=0.f; }
        int rbase = bM + waveM + rt*16 + quad*4;
        for(int ct=0;ct<8;ct++){
            int col = waveN + ct*16 + l16;
            float bv = bf2f(bias[col]);
            for(int r=0;r<4;r++){
                float v = acc[rt][ct][r] + bv + bf2f(Qb[(size_t)(rbase+r)*256 + col]);
                acc[rt][ct][r] = v;
                s[rt][r] += v; s2[rt][r] += v*v;
            }
        }
    }
    for(int m=1;m<16;m<<=1)
        for(int rt=0;rt<2;rt++) for(int r=0;r<4;r++){
            s[rt][r]  += __shfl_xor(s[rt][r],  m);
            s2[rt][r] += __shfl_xor(s2[rt][r], m);
        }
    int wN = wid>>1;
    if(l16==0){
        for(int rt=0;rt<2;rt++) for(int r=0;r<4;r++){
            int row = waveM + rt*16 + quad*4 + r;
            sS [wN][row] = s[rt][r];
            sS2[wN][row] = s2[rt][r];
        }
    }
    __syncthreads();
    for(int rt=0;rt<2;rt++){
        for(int r=0;r<4;r++){
            int row = waveM + rt*16 + quad*4 + r;
            float S    = sS[0][row]  + sS[1][row];
            float S2   = sS2[0][row] + sS2[1][row];
            float mean = S*(1.0f/256.0f);
            float var  = S2*(1.0f/256.0f) - mean*mean;
            float rs   = rsqrtf(var + 1e-5f);
            for(int ct=0;ct<8;ct++){
                int col = waveN + ct*16 + l16;
                float y = (acc[rt][ct][r]-mean)*rs*bf2f(g[col]) + bf2f(be[col]);
                Qb[(size_t)(bM+row)*256 + col] = f2bf(y);
            }
        }
    }
}

// ---- fused decoder: d_w1-GEMM + LN + GELU -> LDS sH -> d_w2-GEMM + GELU
//      -> sH -> final 4-col projection -> out. H1 never touches global.
// rows 0..8191 = visible (KV) ; rows 8192..32767 = masked (MF)
__global__ __launch_bounds__(256) void k_dec(u16* __restrict__ out){
    const u16* A    = g_ws + KV_OFF;
    const u16* Bw1  = g_cvt + DW1_C;
    const u16* b1   = g_cvt + DB1_C;
    const u16* g1   = g_cvt + DG_C;
    const u16* be1  = g_cvt + DBE_C;
    const u16* w2   = g_cvt + DW2_C;
    const u16* b2   = g_cvt + DB2_C;
    const u16* w3   = g_cvt + DW3_C;
    const u16* b3   = g_cvt + DB3_C;
    __shared__ __align__(16) u16 sA[64*40];     // 5 KB
    __shared__ __align__(16) u16 sB[128*40];    // 10 KB
    __shared__ __align__(16) u16 sH[64*136];    // 17.4 KB (H1, then H2)
    __shared__ __align__(16) u16 sW3[512];
    __shared__ float sS[2][64], sS2[2][64];
    int tid = threadIdx.x, wid = tid>>6, lane = tid&63;
    int quad = lane>>4, l16 = lane&15;
    int bM = blockIdx.x*64;
    int waveM = (wid&1)*32, waveN = (wid>>1)*64;
    if(tid < 64) *(uint4*)&sW3[tid*8] = *(const uint4*)&w3[tid*8];

    // ---------------- phase 1: x @ d_w1^T + b1 (K=256, N=128) ----------------
    f32x4 acc[2][4];
    for(int i=0;i<2;i++) for(int j=0;j<4;j++) acc[i][j] = (f32x4){0.f,0.f,0.f,0.f};
    for(int k0=0;k0<256;k0+=32){
        {
            int row = tid>>2, kc = (tid&3)*8;
            *(uint4*)&sA[row*40+kc] = *(const uint4*)&A[(size_t)(bM+row)*256 + k0 + kc];
        }
        for(int i=0;i<2;i++){
            int e = tid + 256*i;
            int row = e>>2, kc = (e&3)*8;
            *(uint4*)&sB[row*40+kc] = *(const uint4*)&Bw1[(size_t)row*256 + k0 + kc];
        }
        __syncthreads();
        bf16x8 af[2], bfr[4];
        for(int rt=0;rt<2;rt++) af [rt] = *(const bf16x8*)&sA[(waveM+rt*16+l16)*40 + quad*8];
        for(int ct=0;ct<4;ct++) bfr[ct] = *(const bf16x8*)&sB[(waveN+ct*16+l16)*40 + quad*8];
        for(int rt=0;rt<2;rt++)
            for(int ct=0;ct<4;ct++)
                acc[rt][ct] = __builtin_amdgcn_mfma_f32_16x16x32_bf16(af[rt], bfr[ct], acc[rt][ct], 0,0,0);
        __syncthreads();
    }
    // LN + GELU epilogue -> sH (identical math to k_dw1_ln)
    {
        float s[2][4], s2[2][4];
        for(int rt=0;rt<2;rt++){
            for(int r=0;r<4;r++){ s[rt][r]=0.f; s2[rt][r]=0.f; }
            for(int ct=0;ct<4;ct++){
                int col = waveN + ct*16 + l16;
                float bv = bf2f(b1[col]);
                for(int r=0;r<4;r++){
                    float v = acc[rt][ct][r] + bv;
                    acc[rt][ct][r] = v;
                    s[rt][r] += v; s2[rt][r] += v*v;
                }
            }
        }
        for(int m=1;m<16;m<<=1)
            for(int rt=0;rt<2;rt++) for(int r=0;r<4;r++){
                s[rt][r]  += __shfl_xor(s[rt][r],  m);
                s2[rt][r] += __shfl_xor(s2[rt][r], m);
            }
        int wN = wid>>1;
        if(l16==0){
            for(int rt=0;rt<2;rt++) for(int r=0;r<4;r++){
                int row = waveM + rt*16 + quad*4 + r;
                sS [wN][row] = s[rt][r];
                sS2[wN][row] = s2[rt][r];
            }
        }
        __syncthreads();
        for(int rt=0;rt<2;rt++){
            for(int r=0;r<4;r++){
                int row = waveM + rt*16 + quad*4 + r;
                float S    = sS[0][row]  + sS[1][row];
                float S2   = sS2[0][row] + sS2[1][row];
                float mean = S*(1.0f/128.0f);
                float var  = S2*(1.0f/128.0f) - mean*mean;
                float rs   = rsqrtf(var + 1e-5f);
                for(int ct=0;ct<4;ct++){
                    int col = waveN + ct*16 + l16;
                    float y = gelu_f((acc[rt][ct][r]-mean)*rs*bf2f(g1[col]) + bf2f(be1[col]));
                    sH[row*136 + col] = f2bf(y);
                }
            }
        }
    }
    __syncthreads();   // sH (H1) complete, visible to all waves

    // ---------------- phase 2: h1 @ d_w2^T + b2 (K=128, N=128) ----------------
    f32x4 a2[2][4];
    for(int i=0;i<2;i++) for(int j=0;j<4;j++) a2[i][j] = (f32x4){0.f,0.f,0.f,0.f};
    for(int k0=0;k0<128;k0+=32){
        for(int i=0;i<2;i++){
            int e = tid + 256*i;
            int row = e>>2, kc = (e&3)*8;
            *(uint4*)&sB[row*40+kc] = *(const uint4*)&w2[(size_t)row*128 + k0 + kc];
        }
        __syncthreads();
        bf16x8 af[2], bfr[4];
        for(int rt=0;rt<2;rt++) af [rt] = *(const bf16x8*)&sH[(waveM+rt*16+l16)*136 + k0 + quad*8];
        for(int ct=0;ct<4;ct++) bfr[ct] = *(const bf16x8*)&sB[(waveN+ct*16+l16)*40 + quad*8];
        for(int rt=0;rt<2;rt++)
            for(int ct=0;ct<4;ct++)
                a2[rt][ct] = __builtin_amdgcn_mfma_f32_16x16x32_bf16(af[rt], bfr[ct], a2[rt][ct], 0,0,0);
        __syncthreads();
    }
    // GELU epilogue -> sH (overwrite; all reads of H1 completed at last barrier)
    for(int ct=0;ct<4;ct++){
        int col = waveN + ct*16 + l16;
        float bv = bf2f(b2[col]);
        for(int rt=0;rt<2;rt++){
            int rbase = waveM + rt*16 + quad*4;
            for(int r=0;r<4;r++)
                sH[(rbase+r)*136 + col] = f2bf(gelu_f(a2[rt][ct][r] + bv));
        }
    }
    __syncthreads();
    // final 4-col projection (vectorized b128 LDS reads)
    int row = tid>>2, o = tid&3;
    float a = bf2f(b3[o]);
    const u16* hp = &sH[row*136];
    const u16* wp = &sW3[o*128];
    for(int k=0;k<128;k+=8){
        bf16x8 hv = *(const bf16x8*)&hp[k];
        bf16x8 wv = *(const bf16x8*)&wp[k];
        #pragma unroll
        for(int j=0;j<8;j++)
            a += bf2f((u16)hv[j]) * bf2f((u16)wv[j]);
    }
    int gr = bM + row, orow;
    if(gr < 8192){ int bb = gr>>9; int p = gr&511; orow = bb*2048 + p; }
    else         { int j  = gr - 8192; int bb = j/1536; int p = j - bb*1536; orow = bb*2048 + 512 + p; }
    if(g_modes[0]){   // encoded was fp32 -> output fp32
        ((float*)out)[(size_t)orow*4 + o] = a;
    } else {
        out[(size_t)orow*4 + o] = f2bf(a);
    }
}

// -------------------------------------------------------------------------
extern "C" void kernel_launch(void* const* d_in, const int* in_sizes, int n_in,
                              void* d_out, int out_size, void* d_ws, size_t ws_size,
                              hipStream_t stream){
    P27 P;
    for(int i=0;i<27;i++) P.p[i] = d_in[i];
    u16* out = (u16*)d_out;

    k_detect  <<<27, 256, 0, stream>>>(P);
    k_cvt     <<<dim3(27,64), 256, 0, stream>>>(P);
    k_posfront<<<8192, 256, 0, stream>>>();
    k_gemm<1> <<<dim3(512,2), 256, 0, stream>>>(G_OFF, PEW2_C, PEB2_C, KV_OFF, QB_OFF, ENC_C, MTOK_C, 32768, 256, 256);
    k_qkv     <<<dim3(640,2), 256, 0, stream>>>();
    k_attn    <<<dim3(128,6), 256, 0, stream>>>(0);
    k_wo_ln   <<<384, 256, 0, stream>>>();
    k_dec     <<<512, 256, 0, stream>>>(out);
}

// Round 16
// 293.182 us; speedup vs baseline: 1.4588x; 1.4588x over previous
//
#include <hip/hip_runtime.h>
#include <math.h>

typedef unsigned short u16;
typedef unsigned int   u32;
typedef __attribute__((ext_vector_type(8))) short bf16x8;
typedef __attribute__((ext_vector_type(4))) short bf16x4;
typedef __attribute__((ext_vector_type(4))) float f32x4;

#if __has_builtin(__builtin_amdgcn_mfma_f32_16x16x16_bf16)
#define MFMA16(a,b,c) __builtin_amdgcn_mfma_f32_16x16x16_bf16(a,b,c,0,0,0)
#else
#define MFMA16(a,b,c) __builtin_amdgcn_mfma_f32_16x16x16bf16_1k(a,b,c,0,0,0)
#endif

// ---- static device workspace (no dependence on ws_size) ----
__device__ __align__(256) u16 g_ws[23068672];
__device__ __align__(16)  u16 g_cvt[2576904];
__device__ u32  g_mm[8];        // sortable-uint min[3] / max[3]
__device__ int  g_modes[32];    // 1 = input was fp32, 0 = bf16

#define G_OFF   0
#define KH_OFF  0
#define VT_OFF  2097152
#define KV_OFF  8388608
#define QB_OFF  10485760
#define QH_OFF  16777216

// g_cvt offsets (u16 units), inputs 0..26
#define ENC_C   0
#define COORD_C 2097152
#define MTOK_C  2195456
#define PEW1_C  2195712
#define PEB1_C  2196480
#define PEG_C   2196736
#define PEBE_C  2196992
#define PEW2_C  2197248
#define PEB2_C  2262784
#define WQ_C    2263040
#define BQ_C    2328576
#define WK_C    2328832
#define BK_C    2394368
#define WV_C    2394624
#define BV_C    2460160
#define WO_C    2460416
#define BO_C    2525952
#define ANG_C   2526208
#define ANB_C   2526464
#define DW1_C   2526720
#define DB1_C   2559488
#define DG_C    2559616
#define DBE_C   2559744
#define DW2_C   2559872
#define DB2_C   2576256
#define DW3_C   2576384
#define DB3_C   2576896

__device__ const int g_cn[27] = {
    2097152,98304,256,768,256,256,256,65536,256,
    65536,256,65536,256,65536,256,65536,256,256,256,
    32768,128,128,128,16384,128,512,4};
__device__ const int g_coff[27] = {
    ENC_C,COORD_C,MTOK_C,PEW1_C,PEB1_C,PEG_C,PEBE_C,PEW2_C,PEB2_C,
    WQ_C,BQ_C,WK_C,BK_C,WV_C,BV_C,WO_C,BO_C,ANG_C,ANB_C,
    DW1_C,DB1_C,DG_C,DBE_C,DW2_C,DB2_C,DW3_C,DB3_C};

struct P27 { const void* p[27]; };

__device__ __forceinline__ float bf2f(u16 v){ return __uint_as_float(((u32)v)<<16); }
__device__ __forceinline__ u16 f2bf(float f){
    u32 u = __float_as_uint(f);
    return (u16)((u + 0x7FFFu + ((u>>16)&1u)) >> 16);
}
__device__ __forceinline__ float gelu_f(float x){
    return 0.5f*x*(1.0f + erff(x*0.70710678118654752440f));
}
__device__ __forceinline__ u32 f2key(float f){
    u32 u = __float_as_uint(f);
    return (u & 0x80000000u) ? ~u : (u | 0x80000000u);
}
__device__ __forceinline__ float key2f(u32 k){
    u32 u = (k & 0x80000000u) ? (k & 0x7FFFFFFFu) : ~k;
    return __uint_as_float(u);
}
__device__ __forceinline__ float exp2_fast(float x){ return __builtin_amdgcn_exp2f(x); }

// --------------------------------------------------- dtype detect ----
__global__ __launch_bounds__(256) void k_detect(P27 P){
    int i = blockIdx.x, tid = threadIdx.x;
    if(i == 0 && tid < 3){ g_mm[tid] = 0xFFFFFFFFu; g_mm[3+tid] = 0u; }
    int n = g_cn[i];
    const u16* s16 = (const u16*)P.p[i];
    __shared__ int c_nz, c_ib, c_nzE;
    if(tid==0){ c_nz=0; c_ib=0; c_nzE=0; }
    __syncthreads();
    int S = n < 2048 ? n : 2048;
    int nz=0, ib=0, nzE=0;
    for(int w = tid; w < S; w += 256){
        u16 v = s16[w];
        if((v & 0x7FFF) != 0){
            nz++;
            int e = (v>>7)&0xFF;
            if(e >= 0x70 && e <= 0x8F) ib++;
            if((w & 1) == 0) nzE++;
        }
    }
    atomicAdd(&c_nz, nz); atomicAdd(&c_ib, ib); atomicAdd(&c_nzE, nzE);
    __syncthreads();
    if(tid==0){
        int totE = (S+1)>>1, totO = S>>1;
        int nzO = c_nz - c_nzE;
        bool A = (c_ib*10 < c_nz*8);
        bool B = (nzO*10 >= totO*9) && (c_nzE*10 <= totE);
        g_modes[i] = (c_nz > 0 && (A || B)) ? 1 : 0;
    }
}

// ------------------------- vectorized convert (+ fused coord min/max) ----
__global__ __launch_bounds__(256) void k_cvt(P27 P){
    int i = blockIdx.x;
    int n4 = g_cn[i] >> 2;
    int mode = g_modes[i];
    u16* dst = g_cvt + g_coff[i];
    int v0 = blockIdx.y*256 + threadIdx.x, step = gridDim.y*256;
    bool isCoord = (i == 1);
    u32 kmn[3] = {0xFFFFFFFFu,0xFFFFFFFFu,0xFFFFFFFFu};
    u32 kmx[3] = {0u,0u,0u};
    if(mode){
        const float4* src = (const float4*)P.p[i];
        for(int v = v0; v < n4; v += step){
            float4 f = src[v];
            ushort4 o = make_ushort4(f2bf(f.x), f2bf(f.y), f2bf(f.z), f2bf(f.w));
            *(ushort4*)&dst[v*4] = o;
            if(isCoord){
                u16 oo[4] = {o.x,o.y,o.z,o.w};
                for(int j=0;j<4;j++){
                    int c = (v + j) % 3;     // (4v+j)%3 == (v+j)%3
                    u32 k = f2key(bf2f(oo[j]));
                    kmn[c] = min(kmn[c], k); kmx[c] = max(kmx[c], k);
                }
            }
        }
    } else {
        const ushort4* src = (const ushort4*)P.p[i];
        for(int v = v0; v < n4; v += step){
            ushort4 o = src[v];
            *(ushort4*)&dst[v*4] = o;
            if(isCoord){
                u16 oo[4] = {o.x,o.y,o.z,o.w};
                for(int j=0;j<4;j++){
                    int c = (v + j) % 3;
                    u32 k = f2key(bf2f(oo[j]));
                    kmn[c] = min(kmn[c], k); kmx[c] = max(kmx[c], k);
                }
            }
        }
    }
    if(isCoord){
        for(int m=1;m<64;m<<=1){
            for(int c=0;c<3;c++){
                kmn[c] = min(kmn[c], (u32)__shfl_xor((int)kmn[c], m));
                kmx[c] = max(kmx[c], (u32)__shfl_xor((int)kmx[c], m));
            }
        }
        if((threadIdx.x & 63) == 0){
            for(int c=0;c<3;c++){
                atomicMin(&g_mm[c], kmn[c]);
                atomicMax(&g_mm[3+c], kmx[c]);
            }
        }
    }
}

// ----------------------------------------------- pos-embed front (to G) ----
__global__ __launch_bounds__(256) void k_posfront(){
    const u16* coord = g_cvt + COORD_C;
    const u16* w1 = g_cvt + PEW1_C;
    const u16* b1 = g_cvt + PEB1_C;
    const u16* g  = g_cvt + PEG_C;
    const u16* be = g_cvt + PEBE_C;
    u16* G = g_ws + G_OFF;
    int tid = threadIdx.x, wid = tid>>6, lane = tid&63;
    int r = blockIdx.x*4 + wid;
    float cn[3];
    for(int c=0;c<3;c++){
        float mn = key2f(g_mm[c]);
        float span = fmaxf(key2f(g_mm[3+c]) - mn, 1.0f);
        cn[c] = (bf2f(coord[r*3+c]) - mn) * (1.0f/span);
    }
    int j0 = lane*4;
    float t[4];
    for(int jj=0;jj<4;jj++){
        int j = j0+jj;
        t[jj] = bf2f(w1[j*3+0])*cn[0] + bf2f(w1[j*3+1])*cn[1] + bf2f(w1[j*3+2])*cn[2] + bf2f(b1[j]);
    }
    float s  = t[0]+t[1]+t[2]+t[3];
    float s2 = t[0]*t[0]+t[1]*t[1]+t[2]*t[2]+t[3]*t[3];
    for(int m=1;m<64;m<<=1){ s += __shfl_xor(s,m); s2 += __shfl_xor(s2,m); }
    float mean = s*(1.0f/256.0f);
    float var  = s2*(1.0f/256.0f) - mean*mean;
    float rs   = rsqrtf(var + 1e-5f);
    u16 o[4];
    for(int jj=0;jj<4;jj++){
        int j = j0+jj;
        float y = (t[jj]-mean)*rs*bf2f(g[j]) + bf2f(be[j]);
        o[jj] = f2bf(gelu_f(y));
    }
    *(ushort4*)&G[(size_t)r*256 + j0] = make_ushort4(o[0],o[1],o[2],o[3]);
}

// ------------------------------------------------------------- GEMM-BT ----
// 64x128 tile with ASYNC global_load_lds staging (verified r11).
// LDS unpadded (stride 32), both-sides block swizzle for bank conflicts.
// EPI 1: pos scatter (KV = C+encoded / Qb = C+mask_token)
template<int EPI>
__global__ __launch_bounds__(256) void k_gemm(int aOff, int bwOff, int biasOff,
        int out0Off, int out1Off, int add0Off, int add1Off, int M, int N, int K){
    const u16* A  = g_ws + aOff;
    const u16* Bw = g_cvt + bwOff;
    const u16* bias = g_cvt + biasOff;
    u16* out0 = g_ws + out0Off;
    u16* out1 = g_ws + out1Off;
    const u16* add0 = g_cvt + add0Off;
    const u16* add1 = g_cvt + add1Off;
    __shared__ __align__(16) u16 sA[64*32];
    __shared__ __align__(16) u16 sB[128*32];
    int tid = threadIdx.x, wid = tid>>6, lane = tid&63;
    int quad = lane>>4, l16 = lane&15;
    int bM = blockIdx.x*64, bN = blockIdx.y*128;
    int waveM = (wid&1)*32, waveN = (wid>>1)*64;
    int rq = quad ^ ((l16>>1)&3);          // swizzled read block
    int sqA = ((tid&3) ^ ((tid>>3)&3))*8;  // swizzled source col (A, e=tid)
    f32x4 acc[2][4];
    for(int i=0;i<2;i++) for(int j=0;j<4;j++) acc[i][j] = (f32x4){0.f,0.f,0.f,0.f};

    for(int k0=0;k0<K;k0+=32){
        {
            int row = tid>>2;
            __builtin_amdgcn_global_load_lds(
                (const u32*)&A[(size_t)(bM+row)*K + k0 + sqA],
                (u32*)&sA[(size_t)(tid>>6)*512], 16, 0, 0);
        }
        for(int i=0;i<2;i++){
            int e = tid + 256*i;
            int row = e>>2, sq = ((e&3) ^ ((e>>3)&3))*8;
            __builtin_amdgcn_global_load_lds(
                (const u32*)&Bw[(size_t)(bN+row)*K + k0 + sq],
                (u32*)&sB[(size_t)(e>>6)*512], 16, 0, 0);
        }
        __syncthreads();
        bf16x8 af[2], bfr[4];
        for(int rt=0;rt<2;rt++) af [rt] = *(const bf16x8*)&sA[(waveM+rt*16+l16)*32 + rq*8];
        for(int ct=0;ct<4;ct++) bfr[ct] = *(const bf16x8*)&sB[(waveN+ct*16+l16)*32 + rq*8];
        for(int rt=0;rt<2;rt++)
            for(int ct=0;ct<4;ct++)
                acc[rt][ct] = __builtin_amdgcn_mfma_f32_16x16x32_bf16(af[rt], bfr[ct], acc[rt][ct], 0,0,0);
        __syncthreads();
    }

    for(int ct=0;ct<4;ct++){
        int col = bN + waveN + ct*16 + l16;
        float bv = bf2f(bias[col]);
        for(int rt=0;rt<2;rt++){
            int rbase = bM + waveM + rt*16 + quad*4;
            for(int r=0;r<4;r++){
                int row = rbase + r;
                float v = acc[rt][ct][r] + bv;
                if(EPI==0){
                    out0[(size_t)row*N + col] = f2bf(v);
                } else {
                    int b = row>>11, p = row&2047;
                    if(p < 512){
                        int kr = (b<<9) + p;
                        out0[(size_t)kr*256 + col] = f2bf(v + bf2f(add0[(size_t)kr*256 + col]));
                    } else {
                        int qr = b*1536 + (p-512);
                        out1[(size_t)qr*256 + col] = f2bf(v + bf2f(add1[col]));
                    }
                }
            }
        }
    }
}

// -------------------------------------- fused Q/K/V projection GEMM ----
// 64-row tiles, async global_load_lds staging (verified r11).
// bx [0,128) K ; [128,256) V ; [256,640) Q
// V scattered into VT with the key-swizzle; Q written PRE-SCALED by cl.
__global__ __launch_bounds__(256) void k_qkv(){
    int bx = blockIdx.x;
    const u16* A = g_ws + KV_OFF;
    const u16* Bw; const u16* bias; int rowBase, mode;
    if(bx < 128)     { rowBase = bx*64;             Bw = g_cvt+WK_C; bias = g_cvt+BK_C; mode = 0; }
    else if(bx < 256){ rowBase = (bx-128)*64;       Bw = g_cvt+WV_C; bias = g_cvt+BV_C; mode = 1; }
    else             { rowBase = 8192+(bx-256)*64;  Bw = g_cvt+WQ_C; bias = g_cvt+BQ_C; mode = 2; }
    __shared__ __align__(16) u16 sA[64*32];
    __shared__ __align__(16) u16 sB[128*32];
    int tid = threadIdx.x, wid = tid>>6, lane = tid&63;
    int quad = lane>>4, l16 = lane&15;
    int bN = blockIdx.y*128;
    int waveM = (wid&1)*32, waveN = (wid>>1)*64;
    int rq = quad ^ ((l16>>1)&3);
    int sqA = ((tid&3) ^ ((tid>>3)&3))*8;
    f32x4 acc[2][4];
    for(int i=0;i<2;i++) for(int j=0;j<4;j++) acc[i][j] = (f32x4){0.f,0.f,0.f,0.f};

    for(int k0=0;k0<256;k0+=32){
        {
            int row = tid>>2;
            __builtin_amdgcn_global_load_lds(
                (const u32*)&A[(size_t)(rowBase+row)*256 + k0 + sqA],
                (u32*)&sA[(size_t)(tid>>6)*512], 16, 0, 0);
        }
        for(int i=0;i<2;i++){
            int e = tid + 256*i;
            int row = e>>2, sq = ((e&3) ^ ((e>>3)&3))*8;
            __builtin_amdgcn_global_load_lds(
                (const u32*)&Bw[(size_t)(bN+row)*256 + k0 + sq],
                (u32*)&sB[(size_t)(e>>6)*512], 16, 0, 0);
        }
        __syncthreads();
        bf16x8 af[2], bfr[4];
        for(int rt=0;rt<2;rt++) af [rt] = *(const bf16x8*)&sA[(waveM+rt*16+l16)*32 + rq*8];
        for(int ct=0;ct<4;ct++) bfr[ct] = *(const bf16x8*)&sB[(waveN+ct*16+l16)*32 + rq*8];
        for(int rt=0;rt<2;rt++)
            for(int ct=0;ct<4;ct++)
                acc[rt][ct] = __builtin_amdgcn_mfma_f32_16x16x32_bf16(af[rt], bfr[ct], acc[rt][ct], 0,0,0);
        __syncthreads();
    }

    u16* Kh = g_ws + KH_OFF;
    u16* VT = g_ws + VT_OFF;
    u16* Qh = g_ws + QH_OFF;
    const float cl = 0.17677669529663688f * 1.4426950408889634f;  // scale*log2e
    for(int ct=0;ct<4;ct++){
        int col = bN + waveN + ct*16 + l16;
        float bv = bf2f(bias[col]);
        for(int rt=0;rt<2;rt++){
            int rbase = rowBase + waveM + rt*16 + quad*4;
            for(int r=0;r<4;r++){
                int row = rbase + r;
                float v = acc[rt][ct][r] + bv;
                if(mode==0){
                    Kh[(size_t)row*256 + col] = f2bf(v);
                } else if(mode==1){
                    int h = col>>5, d = col&31;
                    int b = row>>9, key = row&511;
                    int t = key>>4, q4 = (key>>2)&3, j = key&3;
                    int keyp = ((t>>1)<<5) + (q4<<3) + ((t&1)<<2) + j;
                    VT[(((size_t)(b*8+h)*32 + d)<<9) + keyp] = f2bf(v);
                } else {
                    Qh[(size_t)(row-8192)*256 + col] = f2bf(v * cl);
                }
            }
        }
    }
}

// ----------------------------------------------------------- attention ----
// Swapped-operand QK^T, fully in-register P, Q pre-scaled (verified r7/r11,
// 46 us). qt=2 is the proven optimum of this structure: qt=1 (r9) loses
// staging amortization (+20us), qt=4 (r15) spills to scratch (+130us).
__global__ __launch_bounds__(256, 6) void k_attn(int y0){
    u16* Qh = g_ws + QH_OFF;
    const u16* Kh = g_ws + KH_OFF;
    const u16* VT = g_ws + VT_OFF;
    __shared__ __align__(16) u16 sK[256*40];     // 20 KB
    int tid = threadIdx.x, wid = tid>>6, lane = tid&63;
    int quad = lane>>4, l16 = lane&15;
    int bh = blockIdx.x, b = bh>>3, h = bh&7;

    const u16* kb = &Kh[(size_t)(b*512)*256 + h*32];
    const u16* vb = &VT[(size_t)bh*32*512];
    int qbase = b*1536 + (y0 + blockIdx.y)*128 + wid*32;

    bf16x8 qf[2];
    qf[0] = *(const bf16x8*)&Qh[(size_t)(qbase      + l16)*256 + h*32 + quad*8];
    qf[1] = *(const bf16x8*)&Qh[(size_t)(qbase + 16 + l16)*256 + h*32 + quad*8];
    f32x4 O[2][2];
    float rs_[2] = {0.f, 0.f};
    #pragma unroll
    for(int qt=0;qt<2;qt++){
        O[qt][0] = (f32x4){0.f,0.f,0.f,0.f}; O[qt][1] = (f32x4){0.f,0.f,0.f,0.f};
    }

    for(int ph=0; ph<2; ph++){
        for(int i=0;i<4;i++){
            int e = tid + 256*i;
            int row = e>>2, kc = (e&3)*8;
            *(uint4*)&sK[row*40+kc] = *(const uint4*)&kb[(size_t)(ph*256+row)*256 + kc];
        }
        __syncthreads();
        for(int c=0;c<2;c++){
            #pragma unroll
            for(int tp=0;tp<4;tp++){
                // V fragments for this k-pair: d=l16 (v0) and d=16+l16 (v1)
                const u16* vp = vb + (size_t)l16*512 + ph*256 + c*128 + tp*32 + quad*8;
                bf16x8 v0 = *(const bf16x8*)vp;
                bf16x8 v1 = *(const bf16x8*)(vp + 16*512);
                bf16x4 v0lo = __builtin_shufflevector(v0, v0, 0,1,2,3);
                bf16x4 v0hi = __builtin_shufflevector(v0, v0, 4,5,6,7);
                bf16x4 v1lo = __builtin_shufflevector(v1, v1, 0,1,2,3);
                bf16x4 v1hi = __builtin_shufflevector(v1, v1, 4,5,6,7);
                bf16x8 kf0 = *(const bf16x8*)&sK[(c*128 + tp*32      + l16)*40 + quad*8];
                bf16x8 kf1 = *(const bf16x8*)&sK[(c*128 + tp*32 + 16 + l16)*40 + quad*8];
                #pragma unroll
                for(int qt=0; qt<2; qt++){
                    f32x4 s0 = __builtin_amdgcn_mfma_f32_16x16x32_bf16(kf0, qf[qt], (f32x4){0.f,0.f,0.f,0.f}, 0,0,0);
                    f32x4 s1 = __builtin_amdgcn_mfma_f32_16x16x32_bf16(kf1, qf[qt], (f32x4){0.f,0.f,0.f,0.f}, 0,0,0);
                    float e0 = exp2_fast(s0[0]), e1 = exp2_fast(s0[1]);
                    float e2 = exp2_fast(s0[2]), e3 = exp2_fast(s0[3]);
                    float e4 = exp2_fast(s1[0]), e5 = exp2_fast(s1[1]);
                    float e6 = exp2_fast(s1[2]), e7 = exp2_fast(s1[3]);
                    rs_[qt] += (e0+e1+e2+e3) + (e4+e5+e6+e7);
                    bf16x4 p0, p1;
                    p0[0]=(short)f2bf(e0); p0[1]=(short)f2bf(e1);
                    p0[2]=(short)f2bf(e2); p0[3]=(short)f2bf(e3);
                    p1[0]=(short)f2bf(e4); p1[1]=(short)f2bf(e5);
                    p1[2]=(short)f2bf(e6); p1[3]=(short)f2bf(e7);
                    O[qt][0] = MFMA16(p0, v0lo, O[qt][0]);
                    O[qt][0] = MFMA16(p1, v0hi, O[qt][0]);
                    O[qt][1] = MFMA16(p0, v1lo, O[qt][1]);
                    O[qt][1] = MFMA16(p1, v1hi, O[qt][1]);
                }
            }
        }
        __syncthreads();
    }
    #pragma unroll
    for(int qt=0;qt<2;qt++){
        float rsum = rs_[qt];
        rsum += __shfl_xor(rsum, 16);
        rsum += __shfl_xor(rsum, 32);
        for(int r=0;r<4;r++){
            float inv = 1.0f / __shfl(rsum, quad*4 + r);
            size_t row = (size_t)(qbase + qt*16 + quad*4 + r);
            Qh[row*256 + h*32      + l16] = f2bf(O[qt][0][r]*inv);
            Qh[row*256 + h*32 + 16 + l16] = f2bf(O[qt][1][r]*inv);
        }
    }
}

// ---------------- fused wo-GEMM + residual add + LayerNorm (in-place Qb) ----
// 64x256 tile (full N per block) so each row's LN is block-local.
__global__ __launch_bounds__(256) void k_wo_ln(){
    const u16* A    = g_ws + QH_OFF;
    const u16* Bw   = g_cvt + WO_C;
    const u16* bias = g_cvt + BO_C;
    u16* Qb = g_ws + QB_OFF;
    const u16* g  = g_cvt + ANG_C;
    const u16* be = g_cvt + ANB_C;
    __shared__ __align__(16) u16 sA[64*40];
    __shared__ __align__(16) u16 sB[256*40];
    __shared__ float sS[2][64], sS2[2][64];
    int tid = threadIdx.x, wid = tid>>6, lane = tid&63;
    int quad = lane>>4, l16 = lane&15;
    int bM = blockIdx.x*64;
    int waveM = (wid&1)*32, waveN = (wid>>1)*128;
    f32x4 acc[2][8];
    for(int i=0;i<2;i++) for(int j=0;j<8;j++) acc[i][j] = (f32x4){0.f,0.f,0.f,0.f};

    for(int k0=0;k0<256;k0+=32){
        {
            int row = tid>>2, kc = (tid&3)*8;
            *(uint4*)&sA[row*40+kc] = *(const uint4*)&A[(size_t)(bM+row)*256 + k0 + kc];
        }
        for(int i=0;i<4;i++){
            int e = tid + 256*i;
            int row = e>>2, kc = (e&3)*8;
            *(uint4*)&sB[row*40+kc] = *(const uint4*)&Bw[(size_t)row*256 + k0 + kc];
        }
        __syncthreads();
        bf16x8 af[2], bfr[8];
        for(int rt=0;rt<2;rt++) af [rt] = *(const bf16x8*)&sA[(waveM+rt*16+l16)*40 + quad*8];
        for(int ct=0;ct<8;ct++) bfr[ct] = *(const bf16x8*)&sB[(waveN+ct*16+l16)*40 + quad*8];
        for(int rt=0;rt<2;rt++)
            for(int ct=0;ct<8;ct++)
                acc[rt][ct] = __builtin_amdgcn_mfma_f32_16x16x32_bf16(af[rt], bfr[ct], acc[rt][ct], 0,0,0);
        __syncthreads();
    }

    // x = q + attn_out + bias (kept fp32 in acc), accumulate LN partials
    float s[2][4], s2[2][4];
    for(int rt=0;rt<2;rt++){
        for(int r=0;r<4;r++){ s[rt][r]=0.f; s2[rt][r]=0.f; }
        int rbase = bM + waveM + rt*16 + quad*4;
        for(int ct=0;ct<8;ct++){
            int col = waveN + ct*16 + l16;
            float bv = bf2f(bias[col]);
            for(int r=0;r<4;r++){
                float v = acc[rt][ct][r] + bv + bf2f(Qb[(size_t)(rbase+r)*256 + col]);
                acc[rt][ct][r] = v;
                s[rt][r] += v; s2[rt][r] += v*v;
            }
        }
    }
    for(int m=1;m<16;m<<=1)
        for(int rt=0;rt<2;rt++) for(int r=0;r<4;r++){
            s[rt][r]  += __shfl_xor(s[rt][r],  m);
            s2[rt][r] += __shfl_xor(s2[rt][r], m);
        }
    int wN = wid>>1;
    if(l16==0){
        for(int rt=0;rt<2;rt++) for(int r=0;r<4;r++){
            int row = waveM + rt*16 + quad*4 + r;
            sS [wN][row] = s[rt][r];
            sS2[wN][row] = s2[rt][r];
        }
    }
    __syncthreads();
    for(int rt=0;rt<2;rt++){
        for(int r=0;r<4;r++){
            int row = waveM + rt*16 + quad*4 + r;
            float S    = sS[0][row]  + sS[1][row];
            float S2   = sS2[0][row] + sS2[1][row];
            float mean = S*(1.0f/256.0f);
            float var  = S2*(1.0f/256.0f) - mean*mean;
            float rs   = rsqrtf(var + 1e-5f);
            for(int ct=0;ct<8;ct++){
                int col = waveN + ct*16 + l16;
                float y = (acc[rt][ct][r]-mean)*rs*bf2f(g[col]) + bf2f(be[col]);
                Qb[(size_t)(bM+row)*256 + col] = f2bf(y);
            }
        }
    }
}

// ---- fused decoder: d_w1-GEMM + LN + GELU -> LDS sH -> d_w2-GEMM + GELU
//      -> sH -> final 4-col projection -> out. H1 never touches global.
// rows 0..8191 = visible (KV) ; rows 8192..32767 = masked (MF)
__global__ __launch_bounds__(256) void k_dec(u16* __restrict__ out){
    const u16* A    = g_ws + KV_OFF;
    const u16* Bw1  = g_cvt + DW1_C;
    const u16* b1   = g_cvt + DB1_C;
    const u16* g1   = g_cvt + DG_C;
    const u16* be1  = g_cvt + DBE_C;
    const u16* w2   = g_cvt + DW2_C;
    const u16* b2   = g_cvt + DB2_C;
    const u16* w3   = g_cvt + DW3_C;
    const u16* b3   = g_cvt + DB3_C;
    __shared__ __align__(16) u16 sA[64*40];     // 5 KB
    __shared__ __align__(16) u16 sB[128*40];    // 10 KB
    __shared__ __align__(16) u16 sH[64*136];    // 17.4 KB (H1, then H2)
    __shared__ __align__(16) u16 sW3[512];
    __shared__ float sS[2][64], sS2[2][64];
    int tid = threadIdx.x, wid = tid>>6, lane = tid&63;
    int quad = lane>>4, l16 = lane&15;
    int bM = blockIdx.x*64;
    int waveM = (wid&1)*32, waveN = (wid>>1)*64;
    if(tid < 64) *(uint4*)&sW3[tid*8] = *(const uint4*)&w3[tid*8];

    // ---------------- phase 1: x @ d_w1^T + b1 (K=256, N=128) ----------------
    f32x4 acc[2][4];
    for(int i=0;i<2;i++) for(int j=0;j<4;j++) acc[i][j] = (f32x4){0.f,0.f,0.f,0.f};
    for(int k0=0;k0<256;k0+=32){
        {
            int row = tid>>2, kc = (tid&3)*8;
            *(uint4*)&sA[row*40+kc] = *(const uint4*)&A[(size_t)(bM+row)*256 + k0 + kc];
        }
        for(int i=0;i<2;i++){
            int e = tid + 256*i;
            int row = e>>2, kc = (e&3)*8;
            *(uint4*)&sB[row*40+kc] = *(const uint4*)&Bw1[(size_t)row*256 + k0 + kc];
        }
        __syncthreads();
        bf16x8 af[2], bfr[4];
        for(int rt=0;rt<2;rt++) af [rt] = *(const bf16x8*)&sA[(waveM+rt*16+l16)*40 + quad*8];
        for(int ct=0;ct<4;ct++) bfr[ct] = *(const bf16x8*)&sB[(waveN+ct*16+l16)*40 + quad*8];
        for(int rt=0;rt<2;rt++)
            for(int ct=0;ct<4;ct++)
                acc[rt][ct] = __builtin_amdgcn_mfma_f32_16x16x32_bf16(af[rt], bfr[ct], acc[rt][ct], 0,0,0);
        __syncthreads();
    }
    // LN + GELU epilogue -> sH (identical math to k_dw1_ln)
    {
        float s[2][4], s2[2][4];
        for(int rt=0;rt<2;rt++){
            for(int r=0;r<4;r++){ s[rt][r]=0.f; s2[rt][r]=0.f; }
            for(int ct=0;ct<4;ct++){
                int col = waveN + ct*16 + l16;
                float bv = bf2f(b1[col]);
                for(int r=0;r<4;r++){
                    float v = acc[rt][ct][r] + bv;
                    acc[rt][ct][r] = v;
                    s[rt][r] += v; s2[rt][r] += v*v;
                }
            }
        }
        for(int m=1;m<16;m<<=1)
            for(int rt=0;rt<2;rt++) for(int r=0;r<4;r++){
                s[rt][r]  += __shfl_xor(s[rt][r],  m);
                s2[rt][r] += __shfl_xor(s2[rt][r], m);
            }
        int wN = wid>>1;
        if(l16==0){
            for(int rt=0;rt<2;rt++) for(int r=0;r<4;r++){
                int row = waveM + rt*16 + quad*4 + r;
                sS [wN][row] = s[rt][r];
                sS2[wN][row] = s2[rt][r];
            }
        }
        __syncthreads();
        for(int rt=0;rt<2;rt++){
            for(int r=0;r<4;r++){
                int row = waveM + rt*16 + quad*4 + r;
                float S    = sS[0][row]  + sS[1][row];
                float S2   = sS2[0][row] + sS2[1][row];
                float mean = S*(1.0f/128.0f);
                float var  = S2*(1.0f/128.0f) - mean*mean;
                float rs   = rsqrtf(var + 1e-5f);
                for(int ct=0;ct<4;ct++){
                    int col = waveN + ct*16 + l16;
                    float y = gelu_f((acc[rt][ct][r]-mean)*rs*bf2f(g1[col]) + bf2f(be1[col]));
                    sH[row*136 + col] = f2bf(y);
                }
            }
        }
    }
    __syncthreads();   // sH (H1) complete, visible to all waves

    // ---------------- phase 2: h1 @ d_w2^T + b2 (K=128, N=128) ----------------
    f32x4 a2[2][4];
    for(int i=0;i<2;i++) for(int j=0;j<4;j++) a2[i][j] = (f32x4){0.f,0.f,0.f,0.f};
    for(int k0=0;k0<128;k0+=32){
        for(int i=0;i<2;i++){
            int e = tid + 256*i;
            int row = e>>2, kc = (e&3)*8;
            *(uint4*)&sB[row*40+kc] = *(const uint4*)&w2[(size_t)row*128 + k0 + kc];
        }
        __syncthreads();
        bf16x8 af[2], bfr[4];
        for(int rt=0;rt<2;rt++) af [rt] = *(const bf16x8*)&sH[(waveM+rt*16+l16)*136 + k0 + quad*8];
        for(int ct=0;ct<4;ct++) bfr[ct] = *(const bf16x8*)&sB[(waveN+ct*16+l16)*40 + quad*8];
        for(int rt=0;rt<2;rt++)
            for(int ct=0;ct<4;ct++)
                a2[rt][ct] = __builtin_amdgcn_mfma_f32_16x16x32_bf16(af[rt], bfr[ct], a2[rt][ct], 0,0,0);
        __syncthreads();
    }
    // GELU epilogue -> sH (overwrite; all reads of H1 completed at last barrier)
    for(int ct=0;ct<4;ct++){
        int col = waveN + ct*16 + l16;
        float bv = bf2f(b2[col]);
        for(int rt=0;rt<2;rt++){
            int rbase = waveM + rt*16 + quad*4;
            for(int r=0;r<4;r++)
                sH[(rbase+r)*136 + col] = f2bf(gelu_f(a2[rt][ct][r] + bv));
        }
    }
    __syncthreads();
    // final 4-col projection (vectorized b128 LDS reads)
    int row = tid>>2, o = tid&3;
    float a = bf2f(b3[o]);
    const u16* hp = &sH[row*136];
    const u16* wp = &sW3[o*128];
    for(int k=0;k<128;k+=8){
        bf16x8 hv = *(const bf16x8*)&hp[k];
        bf16x8 wv = *(const bf16x8*)&wp[k];
        #pragma unroll
        for(int j=0;j<8;j++)
            a += bf2f((u16)hv[j]) * bf2f((u16)wv[j]);
    }
    int gr = bM + row, orow;
    if(gr < 8192){ int bb = gr>>9; int p = gr&511; orow = bb*2048 + p; }
    else         { int j  = gr - 8192; int bb = j/1536; int p = j - bb*1536; orow = bb*2048 + 512 + p; }
    if(g_modes[0]){   // encoded was fp32 -> output fp32
        ((float*)out)[(size_t)orow*4 + o] = a;
    } else {
        out[(size_t)orow*4 + o] = f2bf(a);
    }
}

// -------------------------------------------------------------------------
extern "C" void kernel_launch(void* const* d_in, const int* in_sizes, int n_in,
                              void* d_out, int out_size, void* d_ws, size_t ws_size,
                              hipStream_t stream){
    P27 P;
    for(int i=0;i<27;i++) P.p[i] = d_in[i];
    u16* out = (u16*)d_out;

    k_detect  <<<27, 256, 0, stream>>>(P);
    k_cvt     <<<dim3(27,64), 256, 0, stream>>>(P);
    k_posfront<<<8192, 256, 0, stream>>>();
    k_gemm<1> <<<dim3(512,2), 256, 0, stream>>>(G_OFF, PEW2_C, PEB2_C, KV_OFF, QB_OFF, ENC_C, MTOK_C, 32768, 256, 256);
    k_qkv     <<<dim3(640,2), 256, 0, stream>>>();
    k_attn    <<<dim3(128,12), 256, 0, stream>>>(0);
    k_wo_ln   <<<384, 256, 0, stream>>>();
    k_dec     <<<512, 256, 0, stream>>>(out);
}